// Round 12
// baseline (306.588 us; speedup 1.0000x reference)
//
#include <hip/hip_runtime.h>
#include <hip/hip_bf16.h>
#include <hip/hip_fp16.h>

typedef __hip_bfloat16 bf16;
typedef unsigned int u32;
typedef unsigned short u16;

constexpr int N   = 50000;
constexpr int E   = 1600000;
constexpr int C   = 128;             // channels (H * 32)
constexpr int H   = 4;               // heads
constexpr int NB  = 782;             // dst buckets of 64 nodes (782*64 >= 50000)
constexpr int CAP = 2560;            // pairs capacity per bucket (mean 2048, +11 sigma)
constexpr int CHUNK = 1024;          // edges per kbin block (small => TLP)
constexpr float NEG  = 0.2f;
constexpr float SEPS = 1e-16f;
constexpr float LEPS = 1e-5f;

__device__ __forceinline__ float lo16(u32 v) { return __uint_as_float(v << 16); }
__device__ __forceinline__ float hi16(u32 v) { return __uint_as_float(v & 0xFFFF0000u); }

// K1: h = x @ W. 32 nodes/block, each thread: 4 channels (float4) x 4 nodes.
// LDS:FMA ratio 1:16 (was 1:4). h stored bf16. Fused att dots.
__global__ __launch_bounds__(256) void k1_gemm(
    const float* __restrict__ x, const float* __restrict__ W,
    const float* __restrict__ att_s, const float* __restrict__ att_d,
    bf16* __restrict__ hb, float* __restrict__ as_, float* __restrict__ ad_)
{
    const int nb = blockIdx.x * 32;
    const int t  = threadIdx.x;
    __shared__ float sx[32 * 128];
    const float4* xg = (const float4*)(x + (size_t)nb * 128);
    const int maxv = min(32, N - nb) * 32;     // valid float4 count
#pragma unroll
    for (int i = 0; i < 4; ++i) {
        int idx = t + i * 256;
        ((float4*)sx)[idx] = (idx < maxv) ? xg[idx] : make_float4(0.f, 0.f, 0.f, 0.f);
    }
    __syncthreads();

    const int cg = t & 31;            // channel group -> channels c0..c0+3
    const int c0 = cg * 4;
    const int g  = t >> 5;            // node group of 4 (0..7)
    const float* xb = sx + g * 4 * 128;
    float4 acc[4];
#pragma unroll
    for (int j = 0; j < 4; ++j) acc[j] = make_float4(0.f, 0.f, 0.f, 0.f);

    for (int k = 0; k < 128; k += 4) {
        const float4 w0 = *(const float4*)(W + (size_t)(k + 0) * 128 + c0);
        const float4 w1 = *(const float4*)(W + (size_t)(k + 1) * 128 + c0);
        const float4 w2 = *(const float4*)(W + (size_t)(k + 2) * 128 + c0);
        const float4 w3 = *(const float4*)(W + (size_t)(k + 3) * 128 + c0);
#pragma unroll
        for (int j = 0; j < 4; ++j) {
            const float4 xv = *(const float4*)(xb + j * 128 + k);
            acc[j].x = fmaf(xv.x, w0.x, fmaf(xv.y, w1.x, fmaf(xv.z, w2.x, fmaf(xv.w, w3.x, acc[j].x))));
            acc[j].y = fmaf(xv.x, w0.y, fmaf(xv.y, w1.y, fmaf(xv.z, w2.y, fmaf(xv.w, w3.y, acc[j].y))));
            acc[j].z = fmaf(xv.x, w0.z, fmaf(xv.y, w1.z, fmaf(xv.z, w2.z, fmaf(xv.w, w3.z, acc[j].z))));
            acc[j].w = fmaf(xv.x, w0.w, fmaf(xv.y, w1.w, fmaf(xv.z, w2.w, fmaf(xv.w, w3.w, acc[j].w))));
        }
    }

    const float4 asv = *(const float4*)(att_s + c0);
    const float4 adv = *(const float4*)(att_d + c0);
    const int head = cg >> 3;         // 8 channel-groups (32 ch) per head
#pragma unroll
    for (int j = 0; j < 4; ++j) {
        const int node = nb + g * 4 + j;
        const bool valid = node < N;
        if (valid) {
            __hip_bfloat162 p01, p23;
            p01.x = __float2bfloat16(acc[j].x); p01.y = __float2bfloat16(acc[j].y);
            p23.x = __float2bfloat16(acc[j].z); p23.y = __float2bfloat16(acc[j].w);
            *(__hip_bfloat162*)(hb + (size_t)node * 128 + c0)     = p01;
            *(__hip_bfloat162*)(hb + (size_t)node * 128 + c0 + 2) = p23;
        }
        float vs = acc[j].x * asv.x + acc[j].y * asv.y + acc[j].z * asv.z + acc[j].w * asv.w;
        float vd = acc[j].x * adv.x + acc[j].y * adv.y + acc[j].z * adv.z + acc[j].w * adv.w;
#pragma unroll
        for (int off = 1; off < 8; off <<= 1) {   // reduce the 8-lane head cluster
            vs += __shfl_xor(vs, off, 64);
            vd += __shfl_xor(vd, off, 64);
        }
        if (valid && ((cg & 7) == 0)) {
            as_[node * H + head] = vs;
            ad_[node * H + head] = vd;
        }
    }
}

// KBIN: bin edges into NB dst-buckets as packed u32 (src | (dst&63)<<16).
// Two-phase per 1024-edge chunk: LDS count -> global reserve -> scatter.
__global__ __launch_bounds__(256) void kbin(
    const int* __restrict__ ei, u32* __restrict__ gcur, u32* __restrict__ pairs)
{
    __shared__ u32 lcnt[NB], lbase[NB], lfill[NB];
    __shared__ u16 dstl[CHUNK];
    const int t = threadIdx.x;
    const int base = blockIdx.x * CHUNK;
    const int nE = min(CHUNK, E - base);
    for (int i = t; i < NB; i += 256) lcnt[i] = 0;
    __syncthreads();
    for (int i = t; i < nE; i += 256) {
        u32 d = (u32)ei[E + base + i];
        dstl[i] = (u16)d;
        atomicAdd(&lcnt[d >> 6], 1u);
    }
    __syncthreads();
    for (int i = t; i < NB; i += 256) {
        u32 cb = lcnt[i];
        lbase[i] = cb ? atomicAdd(&gcur[i], cb) : 0u;
        lfill[i] = 0u;
    }
    __syncthreads();
    for (int i = t; i < nE; i += 256) {
        u32 src = (u32)ei[base + i];
        u32 dst = (u32)dstl[i];
        u32 b = dst >> 6;
        u32 pos = atomicAdd(&lfill[b], 1u);
        pairs[(size_t)b * CAP + lbase[b] + pos] = src | ((dst & 63u) << 16);
    }
}

// KFILL2: block (512 thr) per bucket. Bucket base via L2-hot scan of gcur,
// per-node count + wave scan -> row_ptr, scatter u16 col + per-head f16
// softmax weights into TRANSPOSED planes whf[h*E + idx].
__global__ __launch_bounds__(512) void kfill2(
    const u32* __restrict__ pairs, const u32* __restrict__ gcur,
    const float4* __restrict__ as4, const float4* __restrict__ ad4,
    int* __restrict__ row_ptr, u16* __restrict__ col, u16* __restrict__ whf)
{
    __shared__ int jcnt[64], joff[64], jcur[64];
    __shared__ float4 adl[64];
    __shared__ u32 ssum[8];
    const int b = blockIdx.x, t = threadIdx.x;
    const int wave = t >> 6, lane = t & 63;
    const int cntb = (int)gcur[b];

    u32 part = 0;
    for (int i = t; i < b; i += 512) part += gcur[i];
#pragma unroll
    for (int off = 32; off; off >>= 1) part += __shfl_xor(part, off, 64);
    if (lane == 0) ssum[wave] = part;
    if (t < 64) {
        jcnt[t] = 0;
        const int n = b * 64 + t;
        adl[t] = (n < N) ? ad4[n] : make_float4(0.f, 0.f, 0.f, 0.f);
    }
    if (b == 0 && t == 511) row_ptr[N] = E;
    __syncthreads();
    const int base = (int)(ssum[0] + ssum[1] + ssum[2] + ssum[3] +
                           ssum[4] + ssum[5] + ssum[6] + ssum[7]);

    const u32* pr = pairs + (size_t)b * CAP;
    for (int i = t; i < cntb; i += 512) atomicAdd(&jcnt[pr[i] >> 16], 1);
    __syncthreads();
    if (t < 64) {
        int v = jcnt[t], incl = v;
#pragma unroll
        for (int off = 1; off < 64; off <<= 1) {
            int u = __shfl_up(incl, off, 64);
            if (t >= off) incl += u;
        }
        joff[t] = incl - v;
        const int n = b * 64 + t;
        if (n < N) row_ptr[n] = base + joff[t];
        jcur[t] = 0;
    }
    __syncthreads();
    for (int i = t; i < cntb; i += 512) {
        const u32 p = pr[i];
        const int j = p >> 16;
        const u32 s = p & 0xFFFFu;
        const int pos = atomicAdd(&jcur[j], 1);
        const int idx = base + joff[j] + pos;
        col[idx] = (u16)s;
        const float4 a = as4[s];
        const float4 d = adl[j];
        float l0 = a.x + d.x, l1 = a.y + d.y, l2 = a.z + d.z, l3 = a.w + d.w;
        l0 = fmaxf(l0, NEG * l0); l1 = fmaxf(l1, NEG * l1);
        l2 = fmaxf(l2, NEG * l2); l3 = fmaxf(l3, NEG * l3);
        __half h0 = __float2half(__expf(l0));
        __half h1 = __float2half(__expf(l1));
        __half h2 = __float2half(__expf(l2));
        __half h3 = __float2half(__expf(l3));
        whf[0 * (size_t)E + idx] = __half_as_ushort(h0);
        whf[1 * (size_t)E + idx] = __half_as_ushort(h1);
        whf[2 * (size_t)E + idx] = __half_as_ushort(h2);
        whf[3 * (size_t)E + idx] = __half_as_ushort(h3);
    }
}

// KD: fused aggregation + bias + LayerNorm + ELU -> f32 out.
// One wave per node; batched uint2 broadcast loads of col & head-plane w.
__global__ __launch_bounds__(256) void kd_agg_ln(
    const int* __restrict__ row_ptr, const u16* __restrict__ col,
    const u16* __restrict__ whf, const u32* __restrict__ hb,
    const float* __restrict__ as_, const float* __restrict__ ad_,
    const float* __restrict__ bias, const float* __restrict__ gamma,
    const float* __restrict__ beta, float* __restrict__ out)
{
    int gid = blockIdx.x * blockDim.x + threadIdx.x;
    int n = gid >> 6;
    if (n >= N) return;
    const int lane = gid & 63;
    const int head = lane >> 4;
    const u16* whh = whf + (size_t)head * E;

    // self-loop term
    float l = as_[n * H + head] + ad_[n * H + head];
    l = fmaxf(l, NEG * l);
    float w = __expf(l);
    float den = w;
    u32 hv = hb[n * 64 + lane];
    float num0 = w * lo16(hv);
    float num1 = w * hi16(hv);

    int k = row_ptr[n];
    const int end = row_ptr[n + 1];
    if ((k & 1) && k < end) {        // peel to even k for 4B-aligned uint2 loads
        const int s = col[k];
        const float ws = __half2float(__ushort_as_half(whh[k]));
        const u32 vs = hb[s * 64 + lane];
        den += ws;
        num0 = fmaf(ws, lo16(vs), num0);
        num1 = fmaf(ws, hi16(vs), num1);
        ++k;
    }
    for (; k + 8 <= end; k += 8) {
        const uint2 ca = *(const uint2*)(col + k);
        const uint2 cb = *(const uint2*)(col + k + 4);
        const uint2 wa = *(const uint2*)(whh + k);
        const uint2 wb = *(const uint2*)(whh + k + 4);
        const int s0 = ca.x & 0xFFFF, s1 = ca.x >> 16;
        const int s2 = ca.y & 0xFFFF, s3 = ca.y >> 16;
        const int s4 = cb.x & 0xFFFF, s5 = cb.x >> 16;
        const int s6 = cb.y & 0xFFFF, s7 = cb.y >> 16;
        const u32 v0 = hb[s0 * 64 + lane], v1 = hb[s1 * 64 + lane];
        const u32 v2 = hb[s2 * 64 + lane], v3 = hb[s3 * 64 + lane];
        const u32 v4 = hb[s4 * 64 + lane], v5 = hb[s5 * 64 + lane];
        const u32 v6 = hb[s6 * 64 + lane], v7 = hb[s7 * 64 + lane];
        const float w0 = __half2float(__ushort_as_half((u16)(wa.x & 0xFFFF)));
        const float w1 = __half2float(__ushort_as_half((u16)(wa.x >> 16)));
        const float w2 = __half2float(__ushort_as_half((u16)(wa.y & 0xFFFF)));
        const float w3 = __half2float(__ushort_as_half((u16)(wa.y >> 16)));
        const float w4 = __half2float(__ushort_as_half((u16)(wb.x & 0xFFFF)));
        const float w5 = __half2float(__ushort_as_half((u16)(wb.x >> 16)));
        const float w6 = __half2float(__ushort_as_half((u16)(wb.y & 0xFFFF)));
        const float w7 = __half2float(__ushort_as_half((u16)(wb.y >> 16)));
        den += ((w0 + w1) + (w2 + w3)) + ((w4 + w5) + (w6 + w7));
        num0 = fmaf(w0, lo16(v0), num0); num1 = fmaf(w0, hi16(v0), num1);
        num0 = fmaf(w1, lo16(v1), num0); num1 = fmaf(w1, hi16(v1), num1);
        num0 = fmaf(w2, lo16(v2), num0); num1 = fmaf(w2, hi16(v2), num1);
        num0 = fmaf(w3, lo16(v3), num0); num1 = fmaf(w3, hi16(v3), num1);
        num0 = fmaf(w4, lo16(v4), num0); num1 = fmaf(w4, hi16(v4), num1);
        num0 = fmaf(w5, lo16(v5), num0); num1 = fmaf(w5, hi16(v5), num1);
        num0 = fmaf(w6, lo16(v6), num0); num1 = fmaf(w6, hi16(v6), num1);
        num0 = fmaf(w7, lo16(v7), num0); num1 = fmaf(w7, hi16(v7), num1);
    }
    for (; k < end; ++k) {
        const int s = col[k];
        const float ws = __half2float(__ushort_as_half(whh[k]));
        const u32 vs = hb[s * 64 + lane];
        den += ws;
        num0 = fmaf(ws, lo16(vs), num0);
        num1 = fmaf(ws, hi16(vs), num1);
    }

    const int c0 = lane * 2;
    const float inv_den = 1.f / (den + SEPS);
    float v0 = num0 * inv_den + bias[c0];
    float v1 = num1 * inv_den + bias[c0 + 1];

    float sum = v0 + v1;
#pragma unroll
    for (int off = 32; off; off >>= 1) sum += __shfl_xor(sum, off, 64);
    const float mu = sum * (1.0f / C);
    const float d0 = v0 - mu, d1 = v1 - mu;
    float sq = d0 * d0 + d1 * d1;
#pragma unroll
    for (int off = 32; off; off >>= 1) sq += __shfl_xor(sq, off, 64);
    const float inv = rsqrtf(sq * (1.0f / C) + LEPS);
    float y0 = d0 * inv * gamma[c0]     + beta[c0];
    float y1 = d1 * inv * gamma[c0 + 1] + beta[c0 + 1];
    y0 = y0 > 0.f ? y0 : __expf(y0) - 1.f;
    y1 = y1 > 0.f ? y1 : __expf(y1) - 1.f;
    float2 o; o.x = y0; o.y = y1;
    *(float2*)(out + (size_t)n * C + c0) = o;
}

extern "C" void kernel_launch(void* const* d_in, const int* in_sizes, int n_in,
                              void* d_out, int out_size, void* d_ws, size_t ws_size,
                              hipStream_t stream)
{
    const float* x     = (const float*)d_in[0];
    const int*   ei    = (const int*)  d_in[1];
    const float* W     = (const float*)d_in[2];
    const float* att_s = (const float*)d_in[3];
    const float* att_d = (const float*)d_in[4];
    const float* bias  = (const float*)d_in[5];
    const float* gamma = (const float*)d_in[6];
    const float* beta  = (const float*)d_in[7];
    float* out = (float*)d_out;

    // ws (~39 MB): hb bf16[N*C] | as_ f32[N*H] | ad_ f32[N*H] | pairs u32[NB*CAP]
    //            | col u16[E] | whf u16[4*E] (transposed planes) | row_ptr | gcur
    char* p = (char*)d_ws;
    bf16*  hb      = (bf16*)p;   p += (size_t)N * C * sizeof(bf16);
    float* as_     = (float*)p;  p += (size_t)N * H * sizeof(float);
    float* ad_     = (float*)p;  p += (size_t)N * H * sizeof(float);
    u32*   pairs   = (u32*)p;    p += (size_t)NB * CAP * sizeof(u32);
    u16*   col     = (u16*)p;    p += ((size_t)E * sizeof(u16) + 15) & ~(size_t)15;
    u16*   whf     = (u16*)p;    p += (size_t)E * 4 * sizeof(u16);
    int*   row_ptr = (int*)p;    p += ((size_t)(N + 1) * sizeof(int) + 15) & ~(size_t)15;
    u32*   gcur    = (u32*)p;

    hipMemsetAsync(gcur, 0, NB * sizeof(u32), stream);
    k1_gemm<<<(N + 31) / 32, 256, 0, stream>>>(x, W, att_s, att_d, hb, as_, ad_);
    kbin<<<(E + CHUNK - 1) / CHUNK, 256, 0, stream>>>(ei, gcur, pairs);
    kfill2<<<NB, 512, 0, stream>>>(pairs, gcur, (const float4*)as_,
                                   (const float4*)ad_, row_ptr, col, whf);
    kd_agg_ln<<<(N * 64) / 256, 256, 0, stream>>>(
        row_ptr, col, whf, (const u32*)hb, as_, ad_, bias, gamma, beta, out);
}